// Round 1
// baseline (231.006 us; speedup 1.0000x reference)
//
#include <hip/hip_runtime.h>
#include <math.h>

// FrequencyAwareHierarchicalEmbedding, MI355X/gfx950
//
// Shapes: B*L = 409600 positions, D = 128, H = 32.
// Inputs (d_in order): fine_ids[BL] i32, coarse_ids[BL] i32,
//   fine_W[1000001*128] f32, coarse_W[10001*128] f32, freq_W[1000001] f32,
//   W1[257*32] f32, b1[32] f32, W2[32] f32, b2[1] f32.
// Output: fused[BL*128] f32 then adjusted_gate[BL] f32, concatenated in d_out.
//
// Strategy:
//  Phase 1 (position-per-lane): each lane owns one position. h[32] accumulators
//    live in VGPRs; W1/b1/W2/b2 accesses are wave-uniform -> compiler emits
//    s_load, so each MLP MAC is a single v_fmac_f32 (157 TF peak path).
//    Embedding rows are streamed per-lane as float4 (full cacheline use since
//    each 512B row is consumed entirely).
//  Phase 2 (wave-cooperative): all 64 lanes blend one position's 128-float row
//    (float2/lane) -> fully coalesced loads/stores. adj/ids handed over via LDS.
//    The fine row re-read should hit L3 (distinct touched rows ~172MB < 256MB).

#define DD 128
#define HH 32

__device__ __forceinline__ float sigmoid_f(float x) {
    return 1.0f / (1.0f + expf(-x));
}

__global__ __launch_bounds__(256, 4) void fahe_kernel(
    const int*   __restrict__ fine_ids,
    const int*   __restrict__ coarse_ids,
    const float* __restrict__ fine_W,
    const float* __restrict__ coarse_W,
    const float* __restrict__ freq_W,
    const float* __restrict__ W1,
    const float* __restrict__ b1,
    const float* __restrict__ W2,
    const float* __restrict__ b2,
    float* __restrict__ out_fused,
    float* __restrict__ out_gate)
{
    const int tid  = threadIdx.x;
    const int lane = tid & 63;
    const int wave = tid >> 6;
    const int blockStart = (int)blockIdx.x * 256;
    const int p = blockStart + tid;

    __shared__ float s_adj[256];
    __shared__ int   s_if[256];
    __shared__ int   s_ic[256];

    // ---------------- Phase 1: gather + MLP gate (one position per lane) ----
    const int idf = fine_ids[p];
    const int idc = coarse_ids[p];
    const float fw = sigmoid_f(freq_W[idf]);

    // byte offsets stay < 2^31 (fine_W is 512MB), int math is safe
    const float4* __restrict__ rowf = (const float4*)(fine_W   + idf * DD);
    const float4* __restrict__ rowc = (const float4*)(coarse_W + idc * DD);

    float h[HH];
    #pragma unroll
    for (int j = 0; j < HH; ++j) h[j] = b1[j];   // uniform -> s_load

    // fine_emb part of combined @ W1  (W1 rows 0..127)
    #pragma unroll 2
    for (int i4 = 0; i4 < DD / 4; ++i4) {
        const float4 c = rowf[i4];
        const float* __restrict__ w = W1 + i4 * 4 * HH;   // uniform address
        #pragma unroll
        for (int j = 0; j < HH; ++j) h[j] = fmaf(w[j         ], c.x, h[j]);
        #pragma unroll
        for (int j = 0; j < HH; ++j) h[j] = fmaf(w[j +     HH], c.y, h[j]);
        #pragma unroll
        for (int j = 0; j < HH; ++j) h[j] = fmaf(w[j + 2 * HH], c.z, h[j]);
        #pragma unroll
        for (int j = 0; j < HH; ++j) h[j] = fmaf(w[j + 3 * HH], c.w, h[j]);
    }
    // coarse_emb part (W1 rows 128..255)
    #pragma unroll 2
    for (int i4 = 0; i4 < DD / 4; ++i4) {
        const float4 c = rowc[i4];
        const float* __restrict__ w = W1 + (DD + i4 * 4) * HH;
        #pragma unroll
        for (int j = 0; j < HH; ++j) h[j] = fmaf(w[j         ], c.x, h[j]);
        #pragma unroll
        for (int j = 0; j < HH; ++j) h[j] = fmaf(w[j +     HH], c.y, h[j]);
        #pragma unroll
        for (int j = 0; j < HH; ++j) h[j] = fmaf(w[j + 2 * HH], c.z, h[j]);
        #pragma unroll
        for (int j = 0; j < HH; ++j) h[j] = fmaf(w[j + 3 * HH], c.w, h[j]);
    }
    // freq_weight feature (W1 row 256)
    {
        const float* __restrict__ w = W1 + 2 * DD * HH;
        #pragma unroll
        for (int j = 0; j < HH; ++j) h[j] = fmaf(w[j], fw, h[j]);
    }

    // gate = sigmoid(relu(h) @ W2 + b2); adjusted = gate * freq_weight
    float s = b2[0];
    #pragma unroll
    for (int j = 0; j < HH; ++j) s = fmaf(fmaxf(h[j], 0.0f), W2[j], s);
    const float adj = sigmoid_f(s) * fw;

    out_gate[p] = adj;                       // coalesced per wave
    s_adj[tid] = adj;
    s_if[tid]  = idf;
    s_ic[tid]  = idc;
    __syncthreads();

    // ---------------- Phase 2: fusion, wave-cooperative (coalesced) ---------
    // Each wave blends its own 64 positions; 64 lanes x float2 = one 128-row.
    const int waveBase = wave * 64;
    const int d0 = lane * 2;
    #pragma unroll 1
    for (int q = 0; q < 64; ++q) {
        const int pos = blockStart + waveBase + q;
        const float a = s_adj[waveBase + q];          // LDS broadcast
        const int jf = s_if[waveBase + q] * DD;
        const int jc = s_ic[waveBase + q] * DD;
        const float2 f2 = *(const float2*)(fine_W   + jf + d0);
        const float2 c2 = *(const float2*)(coarse_W + jc + d0);
        float2 o;
        o.x = a * f2.x + (1.0f - a) * c2.x;
        o.y = a * f2.y + (1.0f - a) * c2.y;
        *(float2*)(out_fused + pos * DD + d0) = o;    // coalesced 512B/instr
    }
}

extern "C" void kernel_launch(void* const* d_in, const int* in_sizes, int n_in,
                              void* d_out, int out_size, void* d_ws, size_t ws_size,
                              hipStream_t stream) {
    const int*   fine_ids   = (const int*)  d_in[0];
    const int*   coarse_ids = (const int*)  d_in[1];
    const float* fine_W     = (const float*)d_in[2];
    const float* coarse_W   = (const float*)d_in[3];
    const float* freq_W     = (const float*)d_in[4];
    const float* W1         = (const float*)d_in[5];
    const float* b1         = (const float*)d_in[6];
    const float* W2         = (const float*)d_in[7];
    const float* b2         = (const float*)d_in[8];

    const int n = in_sizes[0];               // B*L = 409600 (divisible by 256)
    float* out_fused = (float*)d_out;
    float* out_gate  = (float*)d_out + (size_t)n * DD;

    fahe_kernel<<<dim3(n / 256), dim3(256), 0, stream>>>(
        fine_ids, coarse_ids, fine_W, coarse_W, freq_W,
        W1, b1, W2, b2, out_fused, out_gate);
}